// Round 13
// baseline (2820.565 us; speedup 1.0000x reference)
//
#include <hip/hip_runtime.h>
#include <hip/hip_bf16.h>

#define N_NODES 100000
#define N_EDGES 1600000
#define N_GRAPH 1024
#define DIM_BASE 1000
#define DIM_AUG 384
#define DIM_IN 1384
#define KPAD_IN 1408
#define HD 256
#define BN_EPS 1e-5f

typedef _Float16 f16x8 __attribute__((ext_vector_type(8)));
typedef _Float16 f16x4 __attribute__((ext_vector_type(4)));
typedef float f32x4 __attribute__((ext_vector_type(4)));

// barrier that does NOT drain vmcnt: staged global loads stay in flight.
__device__ __forceinline__ void barrier_keep_vmem() {
    __builtin_amdgcn_sched_barrier(0);
    asm volatile("s_waitcnt lgkmcnt(0)\n\ts_barrier" ::: "memory");
    __builtin_amdgcn_sched_barrier(0);
}

// ---------------- utility ----------------
__global__ void zero_kernel(unsigned int* __restrict__ p, int n) {
    int i = blockIdx.x * blockDim.x + threadIdx.x;
    if (i < n) p[i] = 0u;
}

// ---------------- graph prep ----------------
__global__ void count_edges_kernel(const int* __restrict__ dst, int* __restrict__ counts, int e) {
    int i = blockIdx.x * blockDim.x + threadIdx.x;
    if (i < e) atomicAdd(&counts[dst[i]], 1);
}

__global__ __launch_bounds__(256) void deg_bsum_kernel(const int* __restrict__ counts,
                                                       int* __restrict__ bsum, int n) {
    __shared__ int sh[256];
    int t = threadIdx.x;
    int base = blockIdx.x * 1024 + t * 4;
    int s = 0;
    if (base < n) {
        int4 v = *(const int4*)&counts[base];
        s = v.x + v.y + v.z + v.w;
    }
    sh[t] = s;
    __syncthreads();
    for (int off = 128; off > 0; off >>= 1) {
        if (t < off) sh[t] += sh[t + off];
        __syncthreads();
    }
    if (t == 0) bsum[blockIdx.x] = sh[0];
}

__global__ __launch_bounds__(128) void scan_bsum_kernel(const int* __restrict__ bsum,
                                                        int* __restrict__ boff, int nb) {
    __shared__ int sh[128];
    int t = threadIdx.x;
    int v = (t < nb) ? bsum[t] : 0;
    sh[t] = v;
    __syncthreads();
    for (int off = 1; off < 128; off <<= 1) {
        int u = (t >= off) ? sh[t - off] : 0;
        __syncthreads();
        sh[t] += u;
        __syncthreads();
    }
    if (t < nb) boff[t] = sh[t] - v;
}

__global__ __launch_bounds__(256) void emit_csr_kernel(const int* __restrict__ counts,
                                                       const int* __restrict__ boff,
                                                       int* __restrict__ row_ptr,
                                                       int* __restrict__ cursor,
                                                       float* __restrict__ dinv, int n, int etot) {
    __shared__ int sh[256];
    int t = threadIdx.x;
    int base = blockIdx.x * 1024 + t * 4;
    int c0 = 0, c1 = 0, c2 = 0, c3 = 0;
    if (base < n) {
        int4 v = *(const int4*)&counts[base];
        c0 = v.x; c1 = v.y; c2 = v.z; c3 = v.w;
    }
    int s = c0 + c1 + c2 + c3;
    sh[t] = s;
    __syncthreads();
    for (int off = 1; off < 256; off <<= 1) {
        int u = (t >= off) ? sh[t - off] : 0;
        __syncthreads();
        sh[t] += u;
        __syncthreads();
    }
    if (base < n) {
        int run = boff[blockIdx.x] + sh[t] - s;
        int4 rp;
        rp.x = run; run += c0;
        rp.y = run; run += c1;
        rp.z = run; run += c2;
        rp.w = run;
        *(int4*)&row_ptr[base] = rp;
        *(int4*)&cursor[base] = rp;
        float4 dv;
        dv.x = rsqrtf((float)c0 + 1.0f);
        dv.y = rsqrtf((float)c1 + 1.0f);
        dv.z = rsqrtf((float)c2 + 1.0f);
        dv.w = rsqrtf((float)c3 + 1.0f);
        *(float4*)&dinv[base] = dv;
    }
    if (blockIdx.x == 0 && t == 0) row_ptr[n] = etot;
}

__global__ void fill_edges_kernel(const int* __restrict__ src, const int* __restrict__ dst,
                                  int* __restrict__ cursor, int* __restrict__ col, int e) {
    int i = blockIdx.x * blockDim.x + threadIdx.x;
    if (i < e) {
        int pos = atomicAdd(&cursor[dst[i]], 1);
        col[pos] = src[i];
    }
}

// ---------------- B pre-transpose to fragment-ready f16 chunks ----------------
__global__ __launch_bounds__(256) void btrans_kernel(const float* __restrict__ W,
                                                     f16x8* __restrict__ Bt,
                                                     int K, int nchunks) {
    int idx = blockIdx.x * 256 + threadIdx.x;
    if (idx >= nchunks) return;
    int col = idx & 255;
    int kbase = (idx >> 8) * 8;
    f16x8 h;
#pragma unroll
    for (int j = 0; j < 8; ++j) {
        int k = kbase + j;
        float v = (k < K) ? W[(size_t)k * HD + col] : 0.f;
        h[j] = (_Float16)v;
    }
    Bt[idx] = h;
}

// ============ 2-phase pipelined GEMMs (R9 structure), occupancy-forced 8 waves/SIMD ============

// ---------------- fusion: h0 = relu(concat(x,xa) @ W + b), f16 out ----------------
__global__ __launch_bounds__(256, 8) void fusion_mfma_kernel(
        const float* __restrict__ x, const float* __restrict__ xa,
        const f16x8* __restrict__ Bt, const float* __restrict__ bias,
        _Float16* __restrict__ C, int M) {
    __shared__ __align__(16) _Float16 Al[2][64 * 32];
    int tid = threadIdx.x;
    int lane = tid & 63;
    int wc = tid >> 6;
    int l16 = lane & 15, l4 = lane >> 4;
    int row0 = blockIdx.x * 64;

    int srow = tid >> 2;
    int scol = (tid & 3) * 8;
    int ar = row0 + srow;
    int arc = (ar < M) ? ar : (M - 1);
    const float* xr = x + (size_t)arc * DIM_BASE;
    const float* xar = xa + (size_t)arc * DIM_AUG;

    f32x4 acc[4][4];
#pragma unroll
    for (int m = 0; m < 4; ++m)
#pragma unroll
        for (int n = 0; n < 4; ++n) acc[m][n] = (f32x4){0.f, 0.f, 0.f, 0.f};

    float4 fv[2];
    f16x8 Bq[4];

    auto loadA = [&](int t) {
        int col0 = t * 32 + scol;
        if (col0 > 1376) col0 = 1376;
        const float* sp = (col0 < DIM_BASE) ? (xr + col0) : (xar + (col0 - DIM_BASE));
        fv[0] = ((const float4*)sp)[0];
        fv[1] = ((const float4*)sp)[1];
    };
    auto cvwr = [&](int buf) {
        f16x8 h;
        h[0] = (_Float16)fv[0].x; h[1] = (_Float16)fv[0].y;
        h[2] = (_Float16)fv[0].z; h[3] = (_Float16)fv[0].w;
        h[4] = (_Float16)fv[1].x; h[5] = (_Float16)fv[1].y;
        h[6] = (_Float16)fv[1].z; h[7] = (_Float16)fv[1].w;
        *(f16x8*)&Al[buf][srow * 32 + scol] = h;
    };
    auto loadB = [&](int t) {
#pragma unroll
        for (int n = 0; n < 4; ++n)
            Bq[n] = Bt[(size_t)(t * 4 + l4) * 256 + wc * 64 + n * 16 + l16];
    };
    auto compute = [&](int buf) {
#pragma unroll
        for (int m = 0; m < 4; ++m) {
            f16x8 af = *(const f16x8*)&Al[buf][(m * 16 + l16) * 32 + l4 * 8];
#pragma unroll
            for (int n = 0; n < 4; ++n)
                acc[m][n] = __builtin_amdgcn_mfma_f32_16x16x32_f16(af, Bq[n], acc[m][n], 0, 0, 0);
        }
    };

    const int NT = KPAD_IN / 32;  // 44
    loadA(0);
    cvwr(0);
    loadA(1);
    loadB(0);
    barrier_keep_vmem();

    for (int t = 0; t < NT - 1; ++t) {
        cvwr((t + 1) & 1);
        if (t + 2 < NT) loadA(t + 2);
        compute(t & 1);
        loadB(t + 1);
        barrier_keep_vmem();
    }
    compute((NT - 1) & 1);

#pragma unroll
    for (int n = 0; n < 4; ++n) {
        int colF = wc * 64 + n * 16 + l16;
        float bc = bias[colF];
#pragma unroll
        for (int m = 0; m < 4; ++m) {
#pragma unroll
            for (int r = 0; r < 4; ++r) {
                int rowF = row0 + m * 16 + l4 * 4 + r;
                if (rowF < M)
                    C[(size_t)rowF * HD + colF] = (_Float16)fmaxf(acc[m][n][r] + bc, 0.f);
            }
        }
    }
}

// ---------------- hgemm f16-A: t = A @ W, f16 out ----------------
__global__ __launch_bounds__(256, 8) void hgemm_f16_kernel(
        const _Float16* __restrict__ A, const f16x8* __restrict__ Bt,
        _Float16* __restrict__ C, int M) {
    __shared__ __align__(16) _Float16 Al[2][64 * 32];
    int tid = threadIdx.x;
    int lane = tid & 63;
    int wc = tid >> 6;
    int l16 = lane & 15, l4 = lane >> 4;
    int row0 = blockIdx.x * 64;

    int srow = tid >> 2;
    int scol = (tid & 3) * 8;
    int ar = row0 + srow;
    int arc = (ar < M) ? ar : (M - 1);
    const _Float16* arp = A + (size_t)arc * HD + scol;

    f32x4 acc[4][4];
#pragma unroll
    for (int m = 0; m < 4; ++m)
#pragma unroll
        for (int n = 0; n < 4; ++n) acc[m][n] = (f32x4){0.f, 0.f, 0.f, 0.f};

    f16x8 sv;
    f16x8 Bq[4];

    auto loadB = [&](int t) {
#pragma unroll
        for (int n = 0; n < 4; ++n)
            Bq[n] = Bt[(size_t)(t * 4 + l4) * 256 + wc * 64 + n * 16 + l16];
    };
    auto compute = [&](int buf) {
#pragma unroll
        for (int m = 0; m < 4; ++m) {
            f16x8 af = *(const f16x8*)&Al[buf][(m * 16 + l16) * 32 + l4 * 8];
#pragma unroll
            for (int n = 0; n < 4; ++n)
                acc[m][n] = __builtin_amdgcn_mfma_f32_16x16x32_f16(af, Bq[n], acc[m][n], 0, 0, 0);
        }
    };

    const int NT = HD / 32;  // 8
    sv = *(const f16x8*)(arp);
    *(f16x8*)&Al[0][srow * 32 + scol] = sv;
    sv = *(const f16x8*)(arp + 32);
    loadB(0);
    barrier_keep_vmem();

    for (int t = 0; t < NT - 1; ++t) {
        *(f16x8*)&Al[(t + 1) & 1][srow * 32 + scol] = sv;
        if (t + 2 < NT) sv = *(const f16x8*)(arp + (t + 2) * 32);
        compute(t & 1);
        loadB(t + 1);
        barrier_keep_vmem();
    }
    compute((NT - 1) & 1);

#pragma unroll
    for (int n = 0; n < 4; ++n) {
        int colF = wc * 64 + n * 16 + l16;
#pragma unroll
        for (int m = 0; m < 4; ++m) {
#pragma unroll
            for (int r = 0; r < 4; ++r) {
                int rowF = row0 + m * 16 + l4 * 4 + r;
                if (rowF < M)
                    C[(size_t)rowF * HD + colF] = (_Float16)acc[m][n][r];
            }
        }
    }
}

// ---------------- hgemm fp32-A + fused BN+ReLU: t = relu(A*sc+sh) @ W, f16 out ----------------
__global__ __launch_bounds__(256, 8) void hgemm_bn_kernel(
        const float* __restrict__ A, const f16x8* __restrict__ Bt,
        const float* __restrict__ bnp, _Float16* __restrict__ C, int M) {
    __shared__ __align__(16) _Float16 Al[2][64 * 32];
    __shared__ float bns[512];
    int tid = threadIdx.x;
    int lane = tid & 63;
    int wc = tid >> 6;
    int l16 = lane & 15, l4 = lane >> 4;
    int row0 = blockIdx.x * 64;

    int srow = tid >> 2;
    int scol = (tid & 3) * 8;
    int ar = row0 + srow;
    int arc = (ar < M) ? ar : (M - 1);
    const float* arp = A + (size_t)arc * HD + scol;

    f32x4 acc[4][4];
#pragma unroll
    for (int m = 0; m < 4; ++m)
#pragma unroll
        for (int n = 0; n < 4; ++n) acc[m][n] = (f32x4){0.f, 0.f, 0.f, 0.f};

    float fv0[8], fv1[8];
    f16x8 Bq[4];

    auto loadA = [&](int t, float* fv) {
        const float* sp = arp + t * 32;
        float4 v0 = ((const float4*)sp)[0];
        float4 v1 = ((const float4*)sp)[1];
        fv[0] = v0.x; fv[1] = v0.y; fv[2] = v0.z; fv[3] = v0.w;
        fv[4] = v1.x; fv[5] = v1.y; fv[6] = v1.z; fv[7] = v1.w;
    };
    auto cvwr = [&](int t, int buf, const float* fv) {
        int c = t * 32 + scol;
        f16x8 h;
#pragma unroll
        for (int j = 0; j < 8; ++j)
            h[j] = (_Float16)fmaxf(fmaf(fv[j], bns[c + j], bns[HD + c + j]), 0.f);
        *(f16x8*)&Al[buf][srow * 32 + scol] = h;
    };
    auto loadB = [&](int t) {
#pragma unroll
        for (int n = 0; n < 4; ++n)
            Bq[n] = Bt[(size_t)(t * 4 + l4) * 256 + wc * 64 + n * 16 + l16];
    };
    auto compute = [&](int buf) {
#pragma unroll
        for (int m = 0; m < 4; ++m) {
            f16x8 af = *(const f16x8*)&Al[buf][(m * 16 + l16) * 32 + l4 * 8];
#pragma unroll
            for (int n = 0; n < 4; ++n)
                acc[m][n] = __builtin_amdgcn_mfma_f32_16x16x32_f16(af, Bq[n], acc[m][n], 0, 0, 0);
        }
    };

    const int NT = HD / 32;  // 8
    bns[tid] = bnp[tid];
    bns[256 + tid] = bnp[256 + tid];
    loadA(0, fv0);
    loadA(1, fv1);
    loadB(0);
    barrier_keep_vmem();     // bns visible; A(0),A(1),B(0) in flight
    cvwr(0, 0, fv0);
    barrier_keep_vmem();

    for (int t = 0; t < NT - 1; ++t) {
        if ((t & 1) == 0) {
            cvwr(t + 1, (t + 1) & 1, fv1);
            compute(t & 1);
            loadB(t + 1);
            if (t + 2 < NT) loadA(t + 2, fv0);
        } else {
            cvwr(t + 1, (t + 1) & 1, fv0);
            compute(t & 1);
            loadB(t + 1);
            if (t + 2 < NT) loadA(t + 2, fv1);
        }
        barrier_keep_vmem();
    }
    compute((NT - 1) & 1);

#pragma unroll
    for (int n = 0; n < 4; ++n) {
        int colF = wc * 64 + n * 16 + l16;
#pragma unroll
        for (int m = 0; m < 4; ++m) {
#pragma unroll
            for (int r = 0; r < 4; ++r) {
                int rowF = row0 + m * 16 + l4 * 4 + r;
                if (rowF < M)
                    C[(size_t)rowF * HD + colF] = (_Float16)acc[m][n][r];
            }
        }
    }
}

// ---------------- GCN aggregation: wave-per-node, f16 gather, fp32 out, unroll-4 ----------------
__global__ __launch_bounds__(256) void agg_kernel(
        const _Float16* __restrict__ t, const float* __restrict__ dinv,
        const int* __restrict__ row_ptr, const int* __restrict__ col,
        const float* __restrict__ bias, float* __restrict__ outp, int n) {
    int wid = threadIdx.x >> 6;
    int lane = threadIdx.x & 63;
    int i = blockIdx.x * 4 + wid;
    if (i >= n) return;
    int c0 = lane * 4;
    float di = dinv[i];
    float di2 = di * di;
    f16x4 sv = *(const f16x4*)&t[(size_t)i * HD + c0];
    float a0 = (float)sv[0] * di2, a1 = (float)sv[1] * di2;
    float a2 = (float)sv[2] * di2, a3 = (float)sv[3] * di2;
    int e = row_ptr[i], end = row_ptr[i + 1];
    for (; e + 3 < end; e += 4) {
        int s0 = col[e], s1 = col[e + 1], s2 = col[e + 2], s3 = col[e + 3];
        float w0 = dinv[s0] * di, w1 = dinv[s1] * di;
        float w2 = dinv[s2] * di, w3 = dinv[s3] * di;
        f16x4 v0 = *(const f16x4*)&t[(size_t)s0 * HD + c0];
        f16x4 v1 = *(const f16x4*)&t[(size_t)s1 * HD + c0];
        f16x4 v2 = *(const f16x4*)&t[(size_t)s2 * HD + c0];
        f16x4 v3 = *(const f16x4*)&t[(size_t)s3 * HD + c0];
        a0 = fmaf((float)v0[0], w0, a0); a1 = fmaf((float)v0[1], w0, a1);
        a2 = fmaf((float)v0[2], w0, a2); a3 = fmaf((float)v0[3], w0, a3);
        a0 = fmaf((float)v1[0], w1, a0); a1 = fmaf((float)v1[1], w1, a1);
        a2 = fmaf((float)v1[2], w1, a2); a3 = fmaf((float)v1[3], w1, a3);
        a0 = fmaf((float)v2[0], w2, a0); a1 = fmaf((float)v2[1], w2, a1);
        a2 = fmaf((float)v2[2], w2, a2); a3 = fmaf((float)v2[3], w2, a3);
        a0 = fmaf((float)v3[0], w3, a0); a1 = fmaf((float)v3[1], w3, a1);
        a2 = fmaf((float)v3[2], w3, a2); a3 = fmaf((float)v3[3], w3, a3);
    }
    for (; e < end; ++e) {
        int s0 = col[e];
        float w0 = dinv[s0] * di;
        f16x4 v0 = *(const f16x4*)&t[(size_t)s0 * HD + c0];
        a0 = fmaf((float)v0[0], w0, a0); a1 = fmaf((float)v0[1], w0, a1);
        a2 = fmaf((float)v0[2], w0, a2); a3 = fmaf((float)v0[3], w0, a3);
    }
    float4 b = *(const float4*)&bias[c0];
    float4 o;
    o.x = a0 + b.x; o.y = a1 + b.y; o.z = a2 + b.z; o.w = a3 + b.w;
    *(float4*)&outp[(size_t)i * HD + c0] = o;
}

// ---------------- BatchNorm stats ----------------
__global__ __launch_bounds__(256) void bn_stats_kernel(const float* __restrict__ a,
                                                       float* __restrict__ sums, int n) {
    int tid = threadIdx.x;
    int r0 = blockIdx.x * 256;
    int r1 = min(r0 + 256, n);
    float s = 0.f, s2 = 0.f;
    for (int r = r0; r < r1; ++r) {
        float v = a[(size_t)r * HD + tid];
        s += v;
        s2 = fmaf(v, v, s2);
    }
    atomicAdd(&sums[tid], s);
    atomicAdd(&sums[HD + tid], s2);
}

__global__ __launch_bounds__(256) void bn_final_kernel(const float* __restrict__ sums,
                                                       const float* __restrict__ g,
                                                       const float* __restrict__ be,
                                                       float* __restrict__ p, int n) {
    int tid = threadIdx.x;
    float mean = sums[tid] / (float)n;
    float var = sums[HD + tid] / (float)n - mean * mean;
    float sc = g[tid] * rsqrtf(var + BN_EPS);
    p[tid] = sc;
    p[HD + tid] = be[tid] - mean * sc;
}

// ---------------- graph sizes ----------------
__global__ void graph_cnt_kernel(const int* __restrict__ batch, float* __restrict__ cnt, int n) {
    int i = blockIdx.x * blockDim.x + threadIdx.x;
    if (i < n) atomicAdd(&cnt[batch[i]], 1.0f);
}

// ---------------- BN2 apply + relu + mean-pool accumulate (batch sorted) ----------------
__global__ __launch_bounds__(256) void bn_relu_pool_kernel(const float* __restrict__ a,
                                                           const float* __restrict__ p,
                                                           const int* __restrict__ batch,
                                                           float* __restrict__ pooled, int n) {
    int tid = threadIdx.x;
    int n0 = blockIdx.x * 64;
    int n1 = min(n0 + 64, n);
    if (n0 >= n) return;
    float sc = p[tid], sh = p[HD + tid];
    int curg = batch[n0];
    float acc = 0.f;
    for (int i = n0; i < n1; ++i) {
        int g = batch[i];
        if (g != curg) {
            atomicAdd(&pooled[(size_t)curg * HD + tid], acc);
            acc = 0.f;
            curg = g;
        }
        acc += fmaxf(fmaf(a[(size_t)i * HD + tid], sc, sh), 0.f);
    }
    atomicAdd(&pooled[(size_t)curg * HD + tid], acc);
}

// ---------------- head ----------------
__global__ __launch_bounds__(64) void head_kernel(const float* __restrict__ pooled,
                                                  const float* __restrict__ cnt,
                                                  const float* __restrict__ fcW,
                                                  const float* __restrict__ fcb,
                                                  float* __restrict__ outp) {
    int g = blockIdx.x, lane = threadIdx.x;
    float inv = 1.0f / fmaxf(cnt[g], 1.0f);
    float a0 = 0.f, a1 = 0.f;
    for (int j = lane; j < HD; j += 64) {
        float v = pooled[(size_t)g * HD + j] * inv;
        a0 = fmaf(v, fcW[j * 2 + 0], a0);
        a1 = fmaf(v, fcW[j * 2 + 1], a1);
    }
    for (int off = 32; off > 0; off >>= 1) {
        a0 += __shfl_down(a0, off);
        a1 += __shfl_down(a1, off);
    }
    if (lane == 0) {
        float l0 = a0 + fcb[0], l1 = a1 + fcb[1];
        float m = fmaxf(l0, l1);
        float lse = m + logf(expf(l0 - m) + expf(l1 - m));
        outp[g * 2 + 0] = l0 - lse;
        outp[g * 2 + 1] = l1 - lse;
    }
}

extern "C" void kernel_launch(void* const* d_in, const int* in_sizes, int n_in,
                              void* d_out, int out_size, void* d_ws, size_t ws_size,
                              hipStream_t stream) {
    const float* x        = (const float*)d_in[0];
    const float* x_aug    = (const float*)d_in[1];
    const float* fusion_W = (const float*)d_in[2];
    const float* fusion_b = (const float*)d_in[3];
    const float* W0       = (const float*)d_in[4];
    const float* b0       = (const float*)d_in[5];
    const float* g0       = (const float*)d_in[6];
    const float* be0      = (const float*)d_in[7];
    const float* W1       = (const float*)d_in[8];
    const float* b1       = (const float*)d_in[9];
    const float* g1       = (const float*)d_in[10];
    const float* be1      = (const float*)d_in[11];
    const float* fc_W     = (const float*)d_in[12];
    const float* fc_b     = (const float*)d_in[13];
    const int*   eidx     = (const int*)d_in[14];
    const int*   batch    = (const int*)d_in[15];
    float* outp = (float*)d_out;

    const int N = N_NODES, E = N_EDGES, G = N_GRAPH;
    const int* src = eidx;
    const int* dst = eidx + E;

    size_t off = 0;
    char* ws = (char*)d_ws;
    auto take = [&](size_t nbytes) -> void* {
        void* p = ws + off;
        off = (off + nbytes + 255) & ~(size_t)255;
        return p;
    };
    float*     bufA    = (float*)take((size_t)N * HD * 4);      // agg outputs (fp32)
    _Float16*  bufH    = (_Float16*)take((size_t)N * HD * 2);   // h0 (f16)
    _Float16*  bufT    = (_Float16*)take((size_t)N * HD * 2);   // t1/t2 (f16)
    float*     dinv    = (float*)take((size_t)N * 4);
    int*       row_ptr = (int*)take((size_t)(N + 1) * 4);
    int*       cursor  = (int*)take((size_t)N * 4);
    int*       col     = (int*)take((size_t)E * 4);
    float*     bn1p    = (float*)take(512 * 4);
    float*     bn2p    = (float*)take(512 * 4);
    int*       bsum    = (int*)take(128 * 4);
    int*       boff    = (int*)take(128 * 4);
    f16x8*     BtF     = (f16x8*)take((size_t)(KPAD_IN / 8) * 256 * 16);
    f16x8*     Bt0     = (f16x8*)take((size_t)(HD / 8) * 256 * 16);
    f16x8*     Bt1     = (f16x8*)take((size_t)(HD / 8) * 256 * 16);
    size_t zwords = (size_t)N + 512 + 512 + (size_t)G * HD + G;
    unsigned int* zbase = (unsigned int*)take(zwords * 4);
    int*   counts = (int*)zbase;
    float* bn1s   = (float*)(zbase + N);
    float* bn2s   = bn1s + 512;
    float* pooled = bn2s + 512;
    float* cnt    = pooled + (size_t)G * HD;

    const int nchF = (KPAD_IN / 8) * 256;
    const int nchH = (HD / 8) * 256;
    const int nScanB = (N + 1023) / 1024;  // 98

    zero_kernel<<<(int)((zwords + 255) / 256), 256, 0, stream>>>(zbase, (int)zwords);
    count_edges_kernel<<<(E + 255) / 256, 256, 0, stream>>>(dst, counts, E);
    deg_bsum_kernel<<<nScanB, 256, 0, stream>>>(counts, bsum, N);
    scan_bsum_kernel<<<1, 128, 0, stream>>>(bsum, boff, nScanB);
    emit_csr_kernel<<<nScanB, 256, 0, stream>>>(counts, boff, row_ptr, cursor, dinv, N, E);
    fill_edges_kernel<<<(E + 255) / 256, 256, 0, stream>>>(src, dst, cursor, col, E);
    btrans_kernel<<<(nchF + 255) / 256, 256, 0, stream>>>(fusion_W, BtF, DIM_IN, nchF);
    btrans_kernel<<<(nchH + 255) / 256, 256, 0, stream>>>(W0, Bt0, HD, nchH);
    btrans_kernel<<<(nchH + 255) / 256, 256, 0, stream>>>(W1, Bt1, HD, nchH);

    const int gblocks = (N + 63) / 64;  // 1563
    fusion_mfma_kernel<<<gblocks, 256, 0, stream>>>(x, x_aug, BtF, fusion_b, bufH, N);
    hgemm_f16_kernel<<<gblocks, 256, 0, stream>>>(bufH, Bt0, bufT, N);
    agg_kernel<<<(N + 3) / 4, 256, 0, stream>>>(bufT, dinv, row_ptr, col, b0, bufA, N);
    bn_stats_kernel<<<(N + 255) / 256, 256, 0, stream>>>(bufA, bn1s, N);
    bn_final_kernel<<<1, 256, 0, stream>>>(bn1s, g0, be0, bn1p, N);
    hgemm_bn_kernel<<<gblocks, 256, 0, stream>>>(bufA, Bt1, bn1p, bufT, N);
    agg_kernel<<<(N + 3) / 4, 256, 0, stream>>>(bufT, dinv, row_ptr, col, b1, bufA, N);
    bn_stats_kernel<<<(N + 255) / 256, 256, 0, stream>>>(bufA, bn2s, N);
    bn_final_kernel<<<1, 256, 0, stream>>>(bn2s, g1, be1, bn2p, N);
    graph_cnt_kernel<<<(N + 255) / 256, 256, 0, stream>>>(batch, cnt, N);
    bn_relu_pool_kernel<<<(N + 63) / 64, 256, 0, stream>>>(bufA, bn2p, batch, pooled, N);
    head_kernel<<<G, 64, 0, stream>>>(pooled, cnt, fc_W, fc_b, outp);
}

// Round 14
// 958.817 us; speedup vs baseline: 2.9417x; 2.9417x over previous
//
#include <hip/hip_runtime.h>
#include <hip/hip_bf16.h>

#define N_NODES 100000
#define N_EDGES 1600000
#define N_GRAPH 1024
#define DIM_BASE 1000
#define DIM_AUG 384
#define DIM_IN 1384
#define KPAD_IN 1408
#define HD 256
#define BN_EPS 1e-5f

typedef _Float16 f16x8 __attribute__((ext_vector_type(8)));
typedef _Float16 f16x4 __attribute__((ext_vector_type(4)));
typedef float f32x4 __attribute__((ext_vector_type(4)));

// barrier that does NOT drain vmcnt: staged global loads stay in flight.
__device__ __forceinline__ void barrier_keep_vmem() {
    __builtin_amdgcn_sched_barrier(0);
    asm volatile("s_waitcnt lgkmcnt(0)\n\ts_barrier" ::: "memory");
    __builtin_amdgcn_sched_barrier(0);
}

// ---------------- utility ----------------
__global__ void zero_kernel(unsigned int* __restrict__ p, int n) {
    int i = blockIdx.x * blockDim.x + threadIdx.x;
    if (i < n) p[i] = 0u;
}

// ---------------- graph prep ----------------
__global__ void count_edges_kernel(const int* __restrict__ dst, int* __restrict__ counts, int e) {
    int i = blockIdx.x * blockDim.x + threadIdx.x;
    if (i < e) atomicAdd(&counts[dst[i]], 1);
}

__global__ __launch_bounds__(256) void deg_bsum_kernel(const int* __restrict__ counts,
                                                       int* __restrict__ bsum, int n) {
    __shared__ int sh[256];
    int t = threadIdx.x;
    int base = blockIdx.x * 1024 + t * 4;
    int s = 0;
    if (base < n) {
        int4 v = *(const int4*)&counts[base];
        s = v.x + v.y + v.z + v.w;
    }
    sh[t] = s;
    __syncthreads();
    for (int off = 128; off > 0; off >>= 1) {
        if (t < off) sh[t] += sh[t + off];
        __syncthreads();
    }
    if (t == 0) bsum[blockIdx.x] = sh[0];
}

__global__ __launch_bounds__(128) void scan_bsum_kernel(const int* __restrict__ bsum,
                                                        int* __restrict__ boff, int nb) {
    __shared__ int sh[128];
    int t = threadIdx.x;
    int v = (t < nb) ? bsum[t] : 0;
    sh[t] = v;
    __syncthreads();
    for (int off = 1; off < 128; off <<= 1) {
        int u = (t >= off) ? sh[t - off] : 0;
        __syncthreads();
        sh[t] += u;
        __syncthreads();
    }
    if (t < nb) boff[t] = sh[t] - v;
}

__global__ __launch_bounds__(256) void emit_csr_kernel(const int* __restrict__ counts,
                                                       const int* __restrict__ boff,
                                                       int* __restrict__ row_ptr,
                                                       int* __restrict__ cursor,
                                                       float* __restrict__ dinv, int n, int etot) {
    __shared__ int sh[256];
    int t = threadIdx.x;
    int base = blockIdx.x * 1024 + t * 4;
    int c0 = 0, c1 = 0, c2 = 0, c3 = 0;
    if (base < n) {
        int4 v = *(const int4*)&counts[base];
        c0 = v.x; c1 = v.y; c2 = v.z; c3 = v.w;
    }
    int s = c0 + c1 + c2 + c3;
    sh[t] = s;
    __syncthreads();
    for (int off = 1; off < 256; off <<= 1) {
        int u = (t >= off) ? sh[t - off] : 0;
        __syncthreads();
        sh[t] += u;
        __syncthreads();
    }
    if (base < n) {
        int run = boff[blockIdx.x] + sh[t] - s;
        int4 rp;
        rp.x = run; run += c0;
        rp.y = run; run += c1;
        rp.z = run; run += c2;
        rp.w = run;
        *(int4*)&row_ptr[base] = rp;
        *(int4*)&cursor[base] = rp;
        float4 dv;
        dv.x = rsqrtf((float)c0 + 1.0f);
        dv.y = rsqrtf((float)c1 + 1.0f);
        dv.z = rsqrtf((float)c2 + 1.0f);
        dv.w = rsqrtf((float)c3 + 1.0f);
        *(float4*)&dinv[base] = dv;
    }
    if (blockIdx.x == 0 && t == 0) row_ptr[n] = etot;
}

__global__ void fill_edges_kernel(const int* __restrict__ src, const int* __restrict__ dst,
                                  int* __restrict__ cursor, int* __restrict__ col, int e) {
    int i = blockIdx.x * blockDim.x + threadIdx.x;
    if (i < e) {
        int pos = atomicAdd(&cursor[dst[i]], 1);
        col[pos] = src[i];
    }
}

// ---------------- B pre-transpose to fragment-ready f16 chunks ----------------
__global__ __launch_bounds__(256) void btrans_kernel(const float* __restrict__ W,
                                                     f16x8* __restrict__ Bt,
                                                     int K, int nchunks) {
    int idx = blockIdx.x * 256 + threadIdx.x;
    if (idx >= nchunks) return;
    int col = idx & 255;
    int kbase = (idx >> 8) * 8;
    f16x8 h;
#pragma unroll
    for (int j = 0; j < 8; ++j) {
        int k = kbase + j;
        float v = (k < K) ? W[(size_t)k * HD + col] : 0.f;
        h[j] = (_Float16)v;
    }
    Bt[idx] = h;
}

// ============ 2-phase pipelined GEMMs: BM=64, BK=32, 256 thr = 4 waves (R9 best) ============

// ---------------- fusion: h0 = relu(concat(x,xa) @ W + b), f16 out ----------------
__global__ __launch_bounds__(256, 4) void fusion_mfma_kernel(
        const float* __restrict__ x, const float* __restrict__ xa,
        const f16x8* __restrict__ Bt, const float* __restrict__ bias,
        _Float16* __restrict__ C, int M) {
    __shared__ __align__(16) _Float16 Al[2][64 * 32];
    int tid = threadIdx.x;
    int lane = tid & 63;
    int wc = tid >> 6;
    int l16 = lane & 15, l4 = lane >> 4;
    int row0 = blockIdx.x * 64;

    int srow = tid >> 2;
    int scol = (tid & 3) * 8;
    int ar = row0 + srow;
    int arc = (ar < M) ? ar : (M - 1);
    const float* xr = x + (size_t)arc * DIM_BASE;
    const float* xar = xa + (size_t)arc * DIM_AUG;

    f32x4 acc[4][4];
#pragma unroll
    for (int m = 0; m < 4; ++m)
#pragma unroll
        for (int n = 0; n < 4; ++n) acc[m][n] = (f32x4){0.f, 0.f, 0.f, 0.f};

    float4 fv[2];
    f16x8 Bq[4];

    auto loadA = [&](int t) {
        int col0 = t * 32 + scol;
        if (col0 > 1376) col0 = 1376;
        const float* sp = (col0 < DIM_BASE) ? (xr + col0) : (xar + (col0 - DIM_BASE));
        fv[0] = ((const float4*)sp)[0];
        fv[1] = ((const float4*)sp)[1];
    };
    auto cvwr = [&](int buf) {
        f16x8 h;
        h[0] = (_Float16)fv[0].x; h[1] = (_Float16)fv[0].y;
        h[2] = (_Float16)fv[0].z; h[3] = (_Float16)fv[0].w;
        h[4] = (_Float16)fv[1].x; h[5] = (_Float16)fv[1].y;
        h[6] = (_Float16)fv[1].z; h[7] = (_Float16)fv[1].w;
        *(f16x8*)&Al[buf][srow * 32 + scol] = h;
    };
    auto loadB = [&](int t) {
#pragma unroll
        for (int n = 0; n < 4; ++n)
            Bq[n] = Bt[(size_t)(t * 4 + l4) * 256 + wc * 64 + n * 16 + l16];
    };
    auto compute = [&](int buf) {
#pragma unroll
        for (int m = 0; m < 4; ++m) {
            f16x8 af = *(const f16x8*)&Al[buf][(m * 16 + l16) * 32 + l4 * 8];
#pragma unroll
            for (int n = 0; n < 4; ++n)
                acc[m][n] = __builtin_amdgcn_mfma_f32_16x16x32_f16(af, Bq[n], acc[m][n], 0, 0, 0);
        }
    };

    const int NT = KPAD_IN / 32;  // 44
    loadA(0);
    cvwr(0);
    loadA(1);
    loadB(0);
    barrier_keep_vmem();

    for (int t = 0; t < NT - 1; ++t) {
        cvwr((t + 1) & 1);
        if (t + 2 < NT) loadA(t + 2);
        compute(t & 1);
        loadB(t + 1);
        barrier_keep_vmem();
    }
    compute((NT - 1) & 1);

#pragma unroll
    for (int n = 0; n < 4; ++n) {
        int colF = wc * 64 + n * 16 + l16;
        float bc = bias[colF];
#pragma unroll
        for (int m = 0; m < 4; ++m) {
#pragma unroll
            for (int r = 0; r < 4; ++r) {
                int rowF = row0 + m * 16 + l4 * 4 + r;
                if (rowF < M)
                    C[(size_t)rowF * HD + colF] = (_Float16)fmaxf(acc[m][n][r] + bc, 0.f);
            }
        }
    }
}

// ---------------- hgemm f16-A: t = A @ W, f16 out ----------------
__global__ __launch_bounds__(256, 4) void hgemm_f16_kernel(
        const _Float16* __restrict__ A, const f16x8* __restrict__ Bt,
        _Float16* __restrict__ C, int M) {
    __shared__ __align__(16) _Float16 Al[2][64 * 32];
    int tid = threadIdx.x;
    int lane = tid & 63;
    int wc = tid >> 6;
    int l16 = lane & 15, l4 = lane >> 4;
    int row0 = blockIdx.x * 64;

    int srow = tid >> 2;
    int scol = (tid & 3) * 8;
    int ar = row0 + srow;
    int arc = (ar < M) ? ar : (M - 1);
    const _Float16* arp = A + (size_t)arc * HD + scol;

    f32x4 acc[4][4];
#pragma unroll
    for (int m = 0; m < 4; ++m)
#pragma unroll
        for (int n = 0; n < 4; ++n) acc[m][n] = (f32x4){0.f, 0.f, 0.f, 0.f};

    f16x8 sv;
    f16x8 Bq[4];

    auto loadB = [&](int t) {
#pragma unroll
        for (int n = 0; n < 4; ++n)
            Bq[n] = Bt[(size_t)(t * 4 + l4) * 256 + wc * 64 + n * 16 + l16];
    };
    auto compute = [&](int buf) {
#pragma unroll
        for (int m = 0; m < 4; ++m) {
            f16x8 af = *(const f16x8*)&Al[buf][(m * 16 + l16) * 32 + l4 * 8];
#pragma unroll
            for (int n = 0; n < 4; ++n)
                acc[m][n] = __builtin_amdgcn_mfma_f32_16x16x32_f16(af, Bq[n], acc[m][n], 0, 0, 0);
        }
    };

    const int NT = HD / 32;  // 8
    sv = *(const f16x8*)(arp);
    *(f16x8*)&Al[0][srow * 32 + scol] = sv;
    sv = *(const f16x8*)(arp + 32);
    loadB(0);
    barrier_keep_vmem();

    for (int t = 0; t < NT - 1; ++t) {
        *(f16x8*)&Al[(t + 1) & 1][srow * 32 + scol] = sv;
        if (t + 2 < NT) sv = *(const f16x8*)(arp + (t + 2) * 32);
        compute(t & 1);
        loadB(t + 1);
        barrier_keep_vmem();
    }
    compute((NT - 1) & 1);

#pragma unroll
    for (int n = 0; n < 4; ++n) {
        int colF = wc * 64 + n * 16 + l16;
#pragma unroll
        for (int m = 0; m < 4; ++m) {
#pragma unroll
            for (int r = 0; r < 4; ++r) {
                int rowF = row0 + m * 16 + l4 * 4 + r;
                if (rowF < M)
                    C[(size_t)rowF * HD + colF] = (_Float16)acc[m][n][r];
            }
        }
    }
}

// ---------------- hgemm fp32-A + fused BN+ReLU: t = relu(A*sc+sh) @ W, f16 out ----------------
__global__ __launch_bounds__(256, 4) void hgemm_bn_kernel(
        const float* __restrict__ A, const f16x8* __restrict__ Bt,
        const float* __restrict__ bnp, _Float16* __restrict__ C, int M) {
    __shared__ __align__(16) _Float16 Al[2][64 * 32];
    __shared__ float bns[512];
    int tid = threadIdx.x;
    int lane = tid & 63;
    int wc = tid >> 6;
    int l16 = lane & 15, l4 = lane >> 4;
    int row0 = blockIdx.x * 64;

    int srow = tid >> 2;
    int scol = (tid & 3) * 8;
    int ar = row0 + srow;
    int arc = (ar < M) ? ar : (M - 1);
    const float* arp = A + (size_t)arc * HD + scol;

    f32x4 acc[4][4];
#pragma unroll
    for (int m = 0; m < 4; ++m)
#pragma unroll
        for (int n = 0; n < 4; ++n) acc[m][n] = (f32x4){0.f, 0.f, 0.f, 0.f};

    float fv0[8], fv1[8];
    f16x8 Bq[4];

    auto loadA = [&](int t, float* fv) {
        const float* sp = arp + t * 32;
        float4 v0 = ((const float4*)sp)[0];
        float4 v1 = ((const float4*)sp)[1];
        fv[0] = v0.x; fv[1] = v0.y; fv[2] = v0.z; fv[3] = v0.w;
        fv[4] = v1.x; fv[5] = v1.y; fv[6] = v1.z; fv[7] = v1.w;
    };
    auto cvwr = [&](int t, int buf, const float* fv) {
        int c = t * 32 + scol;
        f16x8 h;
#pragma unroll
        for (int j = 0; j < 8; ++j)
            h[j] = (_Float16)fmaxf(fmaf(fv[j], bns[c + j], bns[HD + c + j]), 0.f);
        *(f16x8*)&Al[buf][srow * 32 + scol] = h;
    };
    auto loadB = [&](int t) {
#pragma unroll
        for (int n = 0; n < 4; ++n)
            Bq[n] = Bt[(size_t)(t * 4 + l4) * 256 + wc * 64 + n * 16 + l16];
    };
    auto compute = [&](int buf) {
#pragma unroll
        for (int m = 0; m < 4; ++m) {
            f16x8 af = *(const f16x8*)&Al[buf][(m * 16 + l16) * 32 + l4 * 8];
#pragma unroll
            for (int n = 0; n < 4; ++n)
                acc[m][n] = __builtin_amdgcn_mfma_f32_16x16x32_f16(af, Bq[n], acc[m][n], 0, 0, 0);
        }
    };

    const int NT = HD / 32;  // 8
    bns[tid] = bnp[tid];
    bns[256 + tid] = bnp[256 + tid];
    loadA(0, fv0);
    loadA(1, fv1);
    loadB(0);
    barrier_keep_vmem();     // bns visible; A(0),A(1),B(0) in flight
    cvwr(0, 0, fv0);
    barrier_keep_vmem();

    for (int t = 0; t < NT - 1; ++t) {
        if ((t & 1) == 0) {
            cvwr(t + 1, (t + 1) & 1, fv1);
            compute(t & 1);
            loadB(t + 1);
            if (t + 2 < NT) loadA(t + 2, fv0);
        } else {
            cvwr(t + 1, (t + 1) & 1, fv0);
            compute(t & 1);
            loadB(t + 1);
            if (t + 2 < NT) loadA(t + 2, fv1);
        }
        barrier_keep_vmem();
    }
    compute((NT - 1) & 1);

#pragma unroll
    for (int n = 0; n < 4; ++n) {
        int colF = wc * 64 + n * 16 + l16;
#pragma unroll
        for (int m = 0; m < 4; ++m) {
#pragma unroll
            for (int r = 0; r < 4; ++r) {
                int rowF = row0 + m * 16 + l4 * 4 + r;
                if (rowF < M)
                    C[(size_t)rowF * HD + colF] = (_Float16)acc[m][n][r];
            }
        }
    }
}

// ---------------- GCN aggregation: wave-per-node, f16 gather, fp32 out, unroll-4 ----------------
__global__ __launch_bounds__(256) void agg_kernel(
        const _Float16* __restrict__ t, const float* __restrict__ dinv,
        const int* __restrict__ row_ptr, const int* __restrict__ col,
        const float* __restrict__ bias, float* __restrict__ outp, int n) {
    int wid = threadIdx.x >> 6;
    int lane = threadIdx.x & 63;
    int i = blockIdx.x * 4 + wid;
    if (i >= n) return;
    int c0 = lane * 4;
    float di = dinv[i];
    float di2 = di * di;
    f16x4 sv = *(const f16x4*)&t[(size_t)i * HD + c0];
    float a0 = (float)sv[0] * di2, a1 = (float)sv[1] * di2;
    float a2 = (float)sv[2] * di2, a3 = (float)sv[3] * di2;
    int e = row_ptr[i], end = row_ptr[i + 1];
    for (; e + 3 < end; e += 4) {
        int s0 = col[e], s1 = col[e + 1], s2 = col[e + 2], s3 = col[e + 3];
        float w0 = dinv[s0] * di, w1 = dinv[s1] * di;
        float w2 = dinv[s2] * di, w3 = dinv[s3] * di;
        f16x4 v0 = *(const f16x4*)&t[(size_t)s0 * HD + c0];
        f16x4 v1 = *(const f16x4*)&t[(size_t)s1 * HD + c0];
        f16x4 v2 = *(const f16x4*)&t[(size_t)s2 * HD + c0];
        f16x4 v3 = *(const f16x4*)&t[(size_t)s3 * HD + c0];
        a0 = fmaf((float)v0[0], w0, a0); a1 = fmaf((float)v0[1], w0, a1);
        a2 = fmaf((float)v0[2], w0, a2); a3 = fmaf((float)v0[3], w0, a3);
        a0 = fmaf((float)v1[0], w1, a0); a1 = fmaf((float)v1[1], w1, a1);
        a2 = fmaf((float)v1[2], w1, a2); a3 = fmaf((float)v1[3], w1, a3);
        a0 = fmaf((float)v2[0], w2, a0); a1 = fmaf((float)v2[1], w2, a1);
        a2 = fmaf((float)v2[2], w2, a2); a3 = fmaf((float)v2[3], w2, a3);
        a0 = fmaf((float)v3[0], w3, a0); a1 = fmaf((float)v3[1], w3, a1);
        a2 = fmaf((float)v3[2], w3, a2); a3 = fmaf((float)v3[3], w3, a3);
    }
    for (; e < end; ++e) {
        int s0 = col[e];
        float w0 = dinv[s0] * di;
        f16x4 v0 = *(const f16x4*)&t[(size_t)s0 * HD + c0];
        a0 = fmaf((float)v0[0], w0, a0); a1 = fmaf((float)v0[1], w0, a1);
        a2 = fmaf((float)v0[2], w0, a2); a3 = fmaf((float)v0[3], w0, a3);
    }
    float4 b = *(const float4*)&bias[c0];
    float4 o;
    o.x = a0 + b.x; o.y = a1 + b.y; o.z = a2 + b.z; o.w = a3 + b.w;
    *(float4*)&outp[(size_t)i * HD + c0] = o;
}

// ---------------- BatchNorm stats ----------------
__global__ __launch_bounds__(256) void bn_stats_kernel(const float* __restrict__ a,
                                                       float* __restrict__ sums, int n) {
    int tid = threadIdx.x;
    int r0 = blockIdx.x * 256;
    int r1 = min(r0 + 256, n);
    float s = 0.f, s2 = 0.f;
    for (int r = r0; r < r1; ++r) {
        float v = a[(size_t)r * HD + tid];
        s += v;
        s2 = fmaf(v, v, s2);
    }
    atomicAdd(&sums[tid], s);
    atomicAdd(&sums[HD + tid], s2);
}

__global__ __launch_bounds__(256) void bn_final_kernel(const float* __restrict__ sums,
                                                       const float* __restrict__ g,
                                                       const float* __restrict__ be,
                                                       float* __restrict__ p, int n) {
    int tid = threadIdx.x;
    float mean = sums[tid] / (float)n;
    float var = sums[HD + tid] / (float)n - mean * mean;
    float sc = g[tid] * rsqrtf(var + BN_EPS);
    p[tid] = sc;
    p[HD + tid] = be[tid] - mean * sc;
}

// ---------------- graph sizes ----------------
__global__ void graph_cnt_kernel(const int* __restrict__ batch, float* __restrict__ cnt, int n) {
    int i = blockIdx.x * blockDim.x + threadIdx.x;
    if (i < n) atomicAdd(&cnt[batch[i]], 1.0f);
}

// ---------------- BN2 apply + relu + mean-pool accumulate (batch sorted) ----------------
__global__ __launch_bounds__(256) void bn_relu_pool_kernel(const float* __restrict__ a,
                                                           const float* __restrict__ p,
                                                           const int* __restrict__ batch,
                                                           float* __restrict__ pooled, int n) {
    int tid = threadIdx.x;
    int n0 = blockIdx.x * 64;
    int n1 = min(n0 + 64, n);
    if (n0 >= n) return;
    float sc = p[tid], sh = p[HD + tid];
    int curg = batch[n0];
    float acc = 0.f;
    for (int i = n0; i < n1; ++i) {
        int g = batch[i];
        if (g != curg) {
            atomicAdd(&pooled[(size_t)curg * HD + tid], acc);
            acc = 0.f;
            curg = g;
        }
        acc += fmaxf(fmaf(a[(size_t)i * HD + tid], sc, sh), 0.f);
    }
    atomicAdd(&pooled[(size_t)curg * HD + tid], acc);
}

// ---------------- head ----------------
__global__ __launch_bounds__(64) void head_kernel(const float* __restrict__ pooled,
                                                  const float* __restrict__ cnt,
                                                  const float* __restrict__ fcW,
                                                  const float* __restrict__ fcb,
                                                  float* __restrict__ outp) {
    int g = blockIdx.x, lane = threadIdx.x;
    float inv = 1.0f / fmaxf(cnt[g], 1.0f);
    float a0 = 0.f, a1 = 0.f;
    for (int j = lane; j < HD; j += 64) {
        float v = pooled[(size_t)g * HD + j] * inv;
        a0 = fmaf(v, fcW[j * 2 + 0], a0);
        a1 = fmaf(v, fcW[j * 2 + 1], a1);
    }
    for (int off = 32; off > 0; off >>= 1) {
        a0 += __shfl_down(a0, off);
        a1 += __shfl_down(a1, off);
    }
    if (lane == 0) {
        float l0 = a0 + fcb[0], l1 = a1 + fcb[1];
        float m = fmaxf(l0, l1);
        float lse = m + logf(expf(l0 - m) + expf(l1 - m));
        outp[g * 2 + 0] = l0 - lse;
        outp[g * 2 + 1] = l1 - lse;
    }
}

extern "C" void kernel_launch(void* const* d_in, const int* in_sizes, int n_in,
                              void* d_out, int out_size, void* d_ws, size_t ws_size,
                              hipStream_t stream) {
    const float* x        = (const float*)d_in[0];
    const float* x_aug    = (const float*)d_in[1];
    const float* fusion_W = (const float*)d_in[2];
    const float* fusion_b = (const float*)d_in[3];
    const float* W0       = (const float*)d_in[4];
    const float* b0       = (const float*)d_in[5];
    const float* g0       = (const float*)d_in[6];
    const float* be0      = (const float*)d_in[7];
    const float* W1       = (const float*)d_in[8];
    const float* b1       = (const float*)d_in[9];
    const float* g1       = (const float*)d_in[10];
    const float* be1      = (const float*)d_in[11];
    const float* fc_W     = (const float*)d_in[12];
    const float* fc_b     = (const float*)d_in[13];
    const int*   eidx     = (const int*)d_in[14];
    const int*   batch    = (const int*)d_in[15];
    float* outp = (float*)d_out;

    const int N = N_NODES, E = N_EDGES, G = N_GRAPH;
    const int* src = eidx;
    const int* dst = eidx + E;

    size_t off = 0;
    char* ws = (char*)d_ws;
    auto take = [&](size_t nbytes) -> void* {
        void* p = ws + off;
        off = (off + nbytes + 255) & ~(size_t)255;
        return p;
    };
    float*     bufA    = (float*)take((size_t)N * HD * 4);      // agg outputs (fp32)
    _Float16*  bufH    = (_Float16*)take((size_t)N * HD * 2);   // h0 (f16)
    _Float16*  bufT    = (_Float16*)take((size_t)N * HD * 2);   // t1/t2 (f16)
    float*     dinv    = (float*)take((size_t)N * 4);
    int*       row_ptr = (int*)take((size_t)(N + 1) * 4);
    int*       cursor  = (int*)take((size_t)N * 4);
    int*       col     = (int*)take((size_t)E * 4);
    float*     bn1p    = (float*)take(512 * 4);
    float*     bn2p    = (float*)take(512 * 4);
    int*       bsum    = (int*)take(128 * 4);
    int*       boff    = (int*)take(128 * 4);
    f16x8*     BtF     = (f16x8*)take((size_t)(KPAD_IN / 8) * 256 * 16);
    f16x8*     Bt0     = (f16x8*)take((size_t)(HD / 8) * 256 * 16);
    f16x8*     Bt1     = (f16x8*)take((size_t)(HD / 8) * 256 * 16);
    size_t zwords = (size_t)N + 512 + 512 + (size_t)G * HD + G;
    unsigned int* zbase = (unsigned int*)take(zwords * 4);
    int*   counts = (int*)zbase;
    float* bn1s   = (float*)(zbase + N);
    float* bn2s   = bn1s + 512;
    float* pooled = bn2s + 512;
    float* cnt    = pooled + (size_t)G * HD;

    const int nchF = (KPAD_IN / 8) * 256;
    const int nchH = (HD / 8) * 256;
    const int nScanB = (N + 1023) / 1024;  // 98

    zero_kernel<<<(int)((zwords + 255) / 256), 256, 0, stream>>>(zbase, (int)zwords);
    count_edges_kernel<<<(E + 255) / 256, 256, 0, stream>>>(dst, counts, E);
    deg_bsum_kernel<<<nScanB, 256, 0, stream>>>(counts, bsum, N);
    scan_bsum_kernel<<<1, 128, 0, stream>>>(bsum, boff, nScanB);
    emit_csr_kernel<<<nScanB, 256, 0, stream>>>(counts, boff, row_ptr, cursor, dinv, N, E);
    fill_edges_kernel<<<(E + 255) / 256, 256, 0, stream>>>(src, dst, cursor, col, E);
    btrans_kernel<<<(nchF + 255) / 256, 256, 0, stream>>>(fusion_W, BtF, DIM_IN, nchF);
    btrans_kernel<<<(nchH + 255) / 256, 256, 0, stream>>>(W0, Bt0, HD, nchH);
    btrans_kernel<<<(nchH + 255) / 256, 256, 0, stream>>>(W1, Bt1, HD, nchH);

    const int gblocks = (N + 63) / 64;  // 1563
    fusion_mfma_kernel<<<gblocks, 256, 0, stream>>>(x, x_aug, BtF, fusion_b, bufH, N);
    hgemm_f16_kernel<<<gblocks, 256, 0, stream>>>(bufH, Bt0, bufT, N);
    agg_kernel<<<(N + 3) / 4, 256, 0, stream>>>(bufT, dinv, row_ptr, col, b0, bufA, N);
    bn_stats_kernel<<<(N + 255) / 256, 256, 0, stream>>>(bufA, bn1s, N);
    bn_final_kernel<<<1, 256, 0, stream>>>(bn1s, g0, be0, bn1p, N);
    hgemm_bn_kernel<<<gblocks, 256, 0, stream>>>(bufA, Bt1, bn1p, bufT, N);
    agg_kernel<<<(N + 3) / 4, 256, 0, stream>>>(bufT, dinv, row_ptr, col, b1, bufA, N);
    bn_stats_kernel<<<(N + 255) / 256, 256, 0, stream>>>(bufA, bn2s, N);
    bn_final_kernel<<<1, 256, 0, stream>>>(bn2s, g1, be1, bn2p, N);
    graph_cnt_kernel<<<(N + 255) / 256, 256, 0, stream>>>(batch, cnt, N);
    bn_relu_pool_kernel<<<(N + 63) / 64, 256, 0, stream>>>(bufA, bn2p, batch, pooled, N);
    head_kernel<<<G, 64, 0, stream>>>(pooled, cnt, fc_W, fc_b, outp);
}